// Round 14
// baseline (151.310 us; speedup 1.0000x reference)
//
#include <hip/hip_runtime.h>
#include <math.h>

// Problem constants (B,N,C fixed by the reference setup).
#define BB 16
#define NN 2048
#define CC 64
#define TPB 256
#define ATPB 512          // k_argmax block: 8 waves
#define MROWS 32          // pruned rows per block (8 waves x 4 rows)
#define RPW 4             // rows per wave (the proven R9 inner-loop shape)
#define E_CONST 2.71828182845904523536f

// ---------------------------------------------------------------------------
// K_pre: zero the A accumulator (d_out) everywhere; blocks 0..BB-1 also run
// ballot-based kept/pruned compaction for batch b and zero S[b,:].
// ---------------------------------------------------------------------------
__global__ __launch_bounds__(TPB) void k_pre(const float* __restrict__ keep,
                                             float* __restrict__ outz,
                                             float* __restrict__ S,
                                             int* __restrict__ cntP,
                                             int* __restrict__ cntK,
                                             int* __restrict__ listP,
                                             int* __restrict__ listK) {
    const int tid = threadIdx.x, lane = tid & 63;

    float4* o4 = (float4*)outz + (size_t)blockIdx.x * 1024;
    float4 z = {0.0f, 0.0f, 0.0f, 0.0f};
#pragma unroll
    for (int i = 0; i < 4; ++i) o4[i * TPB + tid] = z;

    const int b = blockIdx.x;
    if (b >= BB) return;

    __shared__ int cP, cK;
    if (tid == 0) { cP = 0; cK = 0; }
    __syncthreads();
    for (int i = tid; i < NN; i += TPB) S[b * NN + i] = 0.0f;
    const unsigned long long lt = (lane == 63) ? 0x7fffffffffffffffull
                                               : ((1ull << lane) - 1ull);
#pragma unroll
    for (int it = 0; it < NN / TPB; ++it) {
        int n = it * TPB + tid;
        bool kp = keep[b * NN + n] != 0.0f;
        unsigned long long mk = __ballot(kp);
        int nk = __popcll(mk);
        int bk = 0, bp = 0;
        if (lane == 0) {
            bk = atomicAdd(&cK, nk);
            bp = atomicAdd(&cP, 64 - nk);
        }
        bk = __shfl(bk, 0); bp = __shfl(bp, 0);
        int pk = __popcll(mk & lt);
        if (kp) listK[b * NN + bk + pk] = n;
        else    listP[b * NN + bp + (lane - pk)] = n;
    }
    __syncthreads();
    if (tid == 0) { cntP[b] = cP; cntK[b] = cK; }
}

// ---------------------------------------------------------------------------
// K_pre2: build colM[b][k4][colp] float4 = k-quad of kept column colp, scaled
// by its inverse L2 norm (computed inline); zeros for colp >= K.
// ---------------------------------------------------------------------------
__global__ __launch_bounds__(TPB) void k_pre2(const float* __restrict__ x,
                                              const int* __restrict__ cntK,
                                              const int* __restrict__ listK,
                                              float4* __restrict__ colM) {
    const int b = blockIdx.y;
    const int colp = blockIdx.x * TPB + threadIdx.x;
    const int K = cntK[b];
    bool ok = colp < K;
    int tok = ok ? listK[b * NN + colp] : 0;
    const float4* x4 = (const float4*)(x + (size_t)b * NN * CC);
    float4 v[16];
    float sq = 0.0f;
#pragma unroll
    for (int k4 = 0; k4 < 16; ++k4) {
        v[k4] = x4[(size_t)tok * 16 + k4];
        sq += v[k4].x * v[k4].x + v[k4].y * v[k4].y
            + v[k4].z * v[k4].z + v[k4].w * v[k4].w;
    }
    float iv = ok ? 1.0f / (sqrtf(sq) + 1e-6f) : 0.0f;
#pragma unroll
    for (int k4 = 0; k4 < 16; ++k4) {
        float4 w = v[k4];
        w.x *= iv; w.y *= iv; w.z *= iv; w.w *= iv;
        colM[((size_t)b * 16 + k4) * NN + colp] = w;
    }
}

// ---------------------------------------------------------------------------
// K3: GEMM-argmax.  Per-wave code is BYTE-IDENTICAL to the proven R9 optimum
// (acc[4][8] + cv[8], unroll 2, VGPR 60, no barriers/LDS); the only change
// is packaging: 8 waves per block (512 thr) x 4 rows = 32 rows/block, which
// halves the number of full-column wave-sweeps -> col L2 traffic 1 GB->0.5 GB
// (~30->15 us of the 73 us).  Occupancy unchanged (2 blocks/CU x 8 waves).
//  - 1-D grid, b = id&15 -> XCD pinning (FETCH ~6.8 MB, colM L2-resident).
// ---------------------------------------------------------------------------
__global__ __launch_bounds__(ATPB, 2) void k_argmax(
    const float* __restrict__ x,      // [B,N,C]
    const float4* __restrict__ colM,  // [B,16,N] float4
    const int*   __restrict__ cntP,
    const int*   __restrict__ cntK,
    const int*   __restrict__ listP,
    const int*   __restrict__ listK,
    float* __restrict__ S,            // [B,N]   zeroed by k_pre
    float* __restrict__ A) {          // [B,N,C] zeroed by k_pre; aliases d_out

    const int b    = blockIdx.x & 15;
    const int tile = blockIdx.x >> 4;
    const int P = cntP[b], K = cntK[b];
    const int base = tile * MROWS;
    if (base >= P) return;

    const int tid = threadIdx.x;
    const int wid = tid >> 6;         // 0..7
    const int lane = tid & 63;

    int rtok[RPW];
#pragma unroll
    for (int r = 0; r < RPW; ++r) {
        int rid = base + wid * RPW + r;
        int tok = (rid < P) ? listP[b * NN + rid] : 0;
        rtok[r] = __builtin_amdgcn_readfirstlane(tok);
    }
    const float4* x4 = (const float4*)(x + (size_t)b * NN * CC);
    const float4* cm = colM + (size_t)b * 16 * NN;

    float    tmax[RPW];
    unsigned msk[RPW];
#pragma unroll
    for (int r = 0; r < RPW; ++r) { tmax[r] = -3.0e38f; msk[r] = 0u; }

    const int ntiles = (K + 511) >> 9;              // dynamic, <= 4

    for (int t = 0; t < ntiles; ++t) {
        const int cstart = t * 512;

        float acc[RPW][8];
#pragma unroll
        for (int r = 0; r < RPW; ++r)
#pragma unroll
            for (int j = 0; j < 8; ++j) acc[r][j] = 0.0f;

#pragma unroll 2
        for (int k4 = 0; k4 < 16; ++k4) {
            float4 rv[RPW];
#pragma unroll
            for (int r = 0; r < RPW; ++r)           // wave-uniform 16B loads
                rv[r] = x4[(size_t)rtok[r] * 16 + k4];
            const float4* cmk = cm + (size_t)k4 * NN + cstart + lane;
            float4 cv[8];
#pragma unroll
            for (int j = 0; j < 8; ++j)             // coalesced b128 streams
                cv[j] = cmk[j * 64];
#pragma unroll
            for (int r = 0; r < RPW; ++r)
#pragma unroll
                for (int j = 0; j < 8; ++j)
                    acc[r][j] = fmaf(rv[r].x, cv[j].x,
                                fmaf(rv[r].y, cv[j].y,
                                fmaf(rv[r].z, cv[j].z,
                                fmaf(rv[r].w, cv[j].w, acc[r][j]))));
        }

#pragma unroll
        for (int r = 0; r < RPW; ++r)
#pragma unroll
            for (int j = 0; j < 8; ++j) {
                int colp = cstart + j * 64 + lane;
                float s = (colp < K) ? acc[r][j] : -1.0e30f;
                unsigned bit = 1u << ((t << 3) | j);
                if (s > tmax[r])       { tmax[r] = s; msk[r] = bit; }
                else if (s == tmax[r])  msk[r] |= bit;
            }
    }

    // ---- edge emission: per wave, per valid row ----
    int nvr = P - base - wid * RPW;
    for (int r = 0; r < RPW; ++r) {
        if (r >= nvr) break;
        float m = tmax[r];
#pragma unroll
        for (int off = 32; off; off >>= 1) m = fmaxf(m, __shfl_xor(m, off, 64));
        int src = rtok[r];
        float xv = x[(size_t)(b * NN + src) * CC + lane];
        float sq = xv * xv;
#pragma unroll
        for (int off = 32; off; off >>= 1) sq += __shfl_xor(sq, off, 64);
        float ivr = 1.0f / (sqrtf(sq) + 1e-6f);
        float wgt = expf(m * ivr);
        unsigned long long bal = __ballot(tmax[r] == m && msk[r] != 0u);
        while (bal) {
            int sl = __ffsll(bal) - 1;
            bal &= bal - 1;
            unsigned mm = __shfl(msk[r], sl);
            while (mm) {
                int bit = __ffs(mm) - 1;
                mm &= mm - 1;
                int colp = ((bit >> 3) * 512) + ((bit & 7) * 64) + sl;
                int dst = listK[b * NN + colp];
                atomicAdd(&A[(size_t)(b * NN + dst) * CC + lane], wgt * xv);
                if (lane == 0) atomicAdd(&S[b * NN + dst], wgt);
            }
        }
    }
}

// ---------------------------------------------------------------------------
// K4: out = (e*x + A) / (e + S).  A aliases d_out (in-place), float4.
// ---------------------------------------------------------------------------
__global__ __launch_bounds__(TPB) void k_finalize(const float* __restrict__ x,
                                                  const float* __restrict__ S,
                                                  float* __restrict__ out) {
    int i = blockIdx.x * TPB + threadIdx.x;
    int row = i >> 4;
    float inv = 1.0f / (E_CONST + S[row]);
    float4 xv = ((const float4*)x)[i];
    float4 av = ((float4*)out)[i];
    float4 o;
    o.x = (xv.x * E_CONST + av.x) * inv;
    o.y = (xv.y * E_CONST + av.y) * inv;
    o.z = (xv.z * E_CONST + av.z) * inv;
    o.w = (xv.w * E_CONST + av.w) * inv;
    ((float4*)out)[i] = o;
}

// ---------------------------------------------------------------------------
extern "C" void kernel_launch(void* const* d_in, const int* in_sizes, int n_in,
                              void* d_out, int out_size, void* d_ws, size_t ws_size,
                              hipStream_t stream) {
    const float* x    = (const float*)d_in[0];
    const float* keep = (const float*)d_in[2];
    float* out = (float*)d_out;

    // ws: (reserved 128KB) | S 128KB | cnts 128B | listP 128KB | listK 128KB | colM 8MB
    char* ws = (char*)d_ws;
    float* S    = (float*)(ws + (128 << 10));
    int*   cntP = (int*)(ws + (256 << 10));
    int*   cntK = cntP + 16;
    int*   listP = (int*)(ws + (256 << 10) + 128);
    int*   listK = listP + BB * NN;
    float4* colM = (float4*)(ws + (1 << 20));

    k_pre<<<512, TPB, 0, stream>>>(keep, out, S, cntP, cntK, listP, listK);

    dim3 gp2(NN / TPB, BB);
    k_pre2<<<gp2, TPB, 0, stream>>>(x, cntK, listK, colM);

    // 1-D grid: b = id & 15 (XCD pinning), tile = id >> 4.
    k_argmax<<<(NN / MROWS) * BB, ATPB, 0, stream>>>(x, colM, cntP, cntK,
                                                     listP, listK, S, out);

    k_finalize<<<(BB * NN * CC / 4) / TPB, TPB, 0, stream>>>(x, S, out);
}

// Round 16
// 146.454 us; speedup vs baseline: 1.0332x; 1.0332x over previous
//
#include <hip/hip_runtime.h>
#include <math.h>

// Problem constants (B,N,C fixed by the reference setup).
#define BB 16
#define NN 2048
#define CC 64
#define TPB 256
#define MROWS 16          // pruned rows per block (4 waves x 4 rows)
#define RPW 4             // rows per wave
#define E_CONST 2.71828182845904523536f

// ---------------------------------------------------------------------------
// K_pre: zero the A accumulator (d_out) everywhere; blocks 0..BB-1 also run
// ballot-based kept/pruned compaction for batch b and zero S[b,:].
// ---------------------------------------------------------------------------
__global__ __launch_bounds__(TPB) void k_pre(const float* __restrict__ keep,
                                             float* __restrict__ outz,
                                             float* __restrict__ S,
                                             int* __restrict__ cntP,
                                             int* __restrict__ cntK,
                                             int* __restrict__ listP,
                                             int* __restrict__ listK) {
    const int tid = threadIdx.x, lane = tid & 63;

    float4* o4 = (float4*)outz + (size_t)blockIdx.x * 1024;
    float4 z = {0.0f, 0.0f, 0.0f, 0.0f};
#pragma unroll
    for (int i = 0; i < 4; ++i) o4[i * TPB + tid] = z;

    const int b = blockIdx.x;
    if (b >= BB) return;

    __shared__ int cP, cK;
    if (tid == 0) { cP = 0; cK = 0; }
    __syncthreads();
    for (int i = tid; i < NN; i += TPB) S[b * NN + i] = 0.0f;
    const unsigned long long lt = (lane == 63) ? 0x7fffffffffffffffull
                                               : ((1ull << lane) - 1ull);
#pragma unroll
    for (int it = 0; it < NN / TPB; ++it) {
        int n = it * TPB + tid;
        bool kp = keep[b * NN + n] != 0.0f;
        unsigned long long mk = __ballot(kp);
        int nk = __popcll(mk);
        int bk = 0, bp = 0;
        if (lane == 0) {
            bk = atomicAdd(&cK, nk);
            bp = atomicAdd(&cP, 64 - nk);
        }
        bk = __shfl(bk, 0); bp = __shfl(bp, 0);
        int pk = __popcll(mk & lt);
        if (kp) listK[b * NN + bk + pk] = n;
        else    listP[b * NN + bp + (lane - pk)] = n;
    }
    __syncthreads();
    if (tid == 0) { cntP[b] = cP; cntK[b] = cK; }
}

// ---------------------------------------------------------------------------
// K_pre2: build colM[b][k4][colp] float4 = k-quad of kept column colp, scaled
// by its inverse L2 norm (computed inline); zeros for colp >= K.
// ---------------------------------------------------------------------------
__global__ __launch_bounds__(TPB) void k_pre2(const float* __restrict__ x,
                                              const int* __restrict__ cntK,
                                              const int* __restrict__ listK,
                                              float4* __restrict__ colM) {
    const int b = blockIdx.y;
    const int colp = blockIdx.x * TPB + threadIdx.x;
    const int K = cntK[b];
    bool ok = colp < K;
    int tok = ok ? listK[b * NN + colp] : 0;
    const float4* x4 = (const float4*)(x + (size_t)b * NN * CC);
    float4 v[16];
    float sq = 0.0f;
#pragma unroll
    for (int k4 = 0; k4 < 16; ++k4) {
        v[k4] = x4[(size_t)tok * 16 + k4];
        sq += v[k4].x * v[k4].x + v[k4].y * v[k4].y
            + v[k4].z * v[k4].z + v[k4].w * v[k4].w;
    }
    float iv = ok ? 1.0f / (sqrtf(sq) + 1e-6f) : 0.0f;
#pragma unroll
    for (int k4 = 0; k4 < 16; ++k4) {
        float4 w = v[k4];
        w.x *= iv; w.y *= iv; w.z *= iv; w.w *= iv;
        colM[((size_t)b * 16 + k4) * NN + colp] = w;
    }
}

// ---------------------------------------------------------------------------
// K3: GEMM-argmax (the R9/R13 optimum, restored exactly; 73 us verified 2x).
// Block = 4 waves x 4 rows; each wave sweeps ALL kept cols (512-col tiles).
//  - acc[4][8] = 32 VGPR + cv[8] = 32 VGPR: the one tile shape this
//    allocator schedules without spilling (VGPR 60) or serializing.
//  - unroll 2 (unroll 4 regressed: VGPR 52, +42% time -- R12).
//  - rows: 4 wave-uniform float4 loads per k4 (L1-resident).
//  - 1-D grid, b = id&15 -> XCD pinning (FETCH ~6.8 MB, colM L2-resident).
//  - NO hand double-buffer / SGPR tricks (R6/R8/R10/R11 all spilled).
//  - cooperative fusion not viable in this harness (R15: silent no-launch).
// ---------------------------------------------------------------------------
__global__ __launch_bounds__(TPB, 4) void k_argmax(
    const float* __restrict__ x,      // [B,N,C]
    const float4* __restrict__ colM,  // [B,16,N] float4
    const int*   __restrict__ cntP,
    const int*   __restrict__ cntK,
    const int*   __restrict__ listP,
    const int*   __restrict__ listK,
    float* __restrict__ S,            // [B,N]   zeroed by k_pre
    float* __restrict__ A) {          // [B,N,C] zeroed by k_pre; aliases d_out

    const int b    = blockIdx.x & 15;
    const int tile = blockIdx.x >> 4;
    const int P = cntP[b], K = cntK[b];
    const int base = tile * MROWS;
    if (base >= P) return;

    const int tid = threadIdx.x;
    const int wid = tid >> 6;
    const int lane = tid & 63;

    int rtok[RPW];
#pragma unroll
    for (int r = 0; r < RPW; ++r) {
        int rid = base + wid * RPW + r;
        int tok = (rid < P) ? listP[b * NN + rid] : 0;
        rtok[r] = __builtin_amdgcn_readfirstlane(tok);
    }
    const float4* x4 = (const float4*)(x + (size_t)b * NN * CC);
    const float4* cm = colM + (size_t)b * 16 * NN;

    float    tmax[RPW];
    unsigned msk[RPW];
#pragma unroll
    for (int r = 0; r < RPW; ++r) { tmax[r] = -3.0e38f; msk[r] = 0u; }

    const int ntiles = (K + 511) >> 9;              // dynamic, <= 4

    for (int t = 0; t < ntiles; ++t) {
        const int cstart = t * 512;

        float acc[RPW][8];
#pragma unroll
        for (int r = 0; r < RPW; ++r)
#pragma unroll
            for (int j = 0; j < 8; ++j) acc[r][j] = 0.0f;

#pragma unroll 2
        for (int k4 = 0; k4 < 16; ++k4) {
            float4 rv[RPW];
#pragma unroll
            for (int r = 0; r < RPW; ++r)           // wave-uniform 16B loads
                rv[r] = x4[(size_t)rtok[r] * 16 + k4];
            const float4* cmk = cm + (size_t)k4 * NN + cstart + lane;
            float4 cv[8];
#pragma unroll
            for (int j = 0; j < 8; ++j)             // coalesced b128 streams
                cv[j] = cmk[j * 64];
#pragma unroll
            for (int r = 0; r < RPW; ++r)
#pragma unroll
                for (int j = 0; j < 8; ++j)
                    acc[r][j] = fmaf(rv[r].x, cv[j].x,
                                fmaf(rv[r].y, cv[j].y,
                                fmaf(rv[r].z, cv[j].z,
                                fmaf(rv[r].w, cv[j].w, acc[r][j]))));
        }

#pragma unroll
        for (int r = 0; r < RPW; ++r)
#pragma unroll
            for (int j = 0; j < 8; ++j) {
                int colp = cstart + j * 64 + lane;
                float s = (colp < K) ? acc[r][j] : -1.0e30f;
                unsigned bit = 1u << ((t << 3) | j);
                if (s > tmax[r])       { tmax[r] = s; msk[r] = bit; }
                else if (s == tmax[r])  msk[r] |= bit;
            }
    }

    // ---- edge emission: per wave, per valid row ----
    int nvr = P - base - wid * RPW;
    for (int r = 0; r < RPW; ++r) {
        if (r >= nvr) break;
        float m = tmax[r];
#pragma unroll
        for (int off = 32; off; off >>= 1) m = fmaxf(m, __shfl_xor(m, off, 64));
        int src = rtok[r];
        float xv = x[(size_t)(b * NN + src) * CC + lane];
        float sq = xv * xv;
#pragma unroll
        for (int off = 32; off; off >>= 1) sq += __shfl_xor(sq, off, 64);
        float ivr = 1.0f / (sqrtf(sq) + 1e-6f);
        float wgt = expf(m * ivr);
        unsigned long long bal = __ballot(tmax[r] == m && msk[r] != 0u);
        while (bal) {
            int sl = __ffsll(bal) - 1;
            bal &= bal - 1;
            unsigned mm = __shfl(msk[r], sl);
            while (mm) {
                int bit = __ffs(mm) - 1;
                mm &= mm - 1;
                int colp = ((bit >> 3) * 512) + ((bit & 7) * 64) + sl;
                int dst = listK[b * NN + colp];
                atomicAdd(&A[(size_t)(b * NN + dst) * CC + lane], wgt * xv);
                if (lane == 0) atomicAdd(&S[b * NN + dst], wgt);
            }
        }
    }
}

// ---------------------------------------------------------------------------
// K4: out = (e*x + A) / (e + S).  A aliases d_out (in-place), float4.
// ---------------------------------------------------------------------------
__global__ __launch_bounds__(TPB) void k_finalize(const float* __restrict__ x,
                                                  const float* __restrict__ S,
                                                  float* __restrict__ out) {
    int i = blockIdx.x * TPB + threadIdx.x;
    int row = i >> 4;
    float inv = 1.0f / (E_CONST + S[row]);
    float4 xv = ((const float4*)x)[i];
    float4 av = ((float4*)out)[i];
    float4 o;
    o.x = (xv.x * E_CONST + av.x) * inv;
    o.y = (xv.y * E_CONST + av.y) * inv;
    o.z = (xv.z * E_CONST + av.z) * inv;
    o.w = (xv.w * E_CONST + av.w) * inv;
    ((float4*)out)[i] = o;
}

// ---------------------------------------------------------------------------
extern "C" void kernel_launch(void* const* d_in, const int* in_sizes, int n_in,
                              void* d_out, int out_size, void* d_ws, size_t ws_size,
                              hipStream_t stream) {
    const float* x    = (const float*)d_in[0];
    const float* keep = (const float*)d_in[2];
    float* out = (float*)d_out;

    // ws: (reserved 128KB) | S 128KB | cnts 128B | listP 128KB | listK 128KB | colM 8MB
    char* ws = (char*)d_ws;
    float* S    = (float*)(ws + (128 << 10));
    int*   cntP = (int*)(ws + (256 << 10));
    int*   cntK = cntP + 16;
    int*   listP = (int*)(ws + (256 << 10) + 128);
    int*   listK = listP + BB * NN;
    float4* colM = (float4*)(ws + (1 << 20));

    k_pre<<<512, TPB, 0, stream>>>(keep, out, S, cntP, cntK, listP, listK);

    dim3 gp2(NN / TPB, BB);
    k_pre2<<<gp2, TPB, 0, stream>>>(x, cntK, listK, colM);

    // 1-D grid: b = id & 15 (XCD pinning), tile = id >> 4.
    k_argmax<<<(NN / MROWS) * BB, TPB, 0, stream>>>(x, colM, cntP, cntK,
                                                    listP, listK, S, out);

    k_finalize<<<(BB * NN * CC / 4) / TPB, TPB, 0, stream>>>(x, S, out);
}